// Round 5
// baseline (1339.010 us; speedup 1.0000x reference)
//
#include <hip/hip_runtime.h>
#include <hip/hip_bf16.h>
#include <math.h>

// Problem constants
#define GG 33538
#define DD 256
#define LL 6
#define HH 8
#define KK 2048
#define BB 4
#define TT 2049          // K+1 tokens
#define BT (BB*TT)       // 8196
#define NT 65            // 32-key tiles per (b,h)

typedef __bf16 bf16x8 __attribute__((ext_vector_type(8)));
typedef float f32x4 __attribute__((ext_vector_type(4)));
typedef float f32x16 __attribute__((ext_vector_type(16)));
typedef unsigned short ub16;

union BW { __bf16 h; ub16 u; };
__device__ __forceinline__ ub16 f2b(float x) { BW w; w.h = (__bf16)x; return w.u; }
__device__ __forceinline__ unsigned pk2(float a, float b) {
    return (unsigned)f2b(a) | ((unsigned)f2b(b) << 16);
}
union U4B { unsigned u[4]; bf16x8 v; };

__device__ __forceinline__ float gelu_f(float x) {
    return 0.5f * x * (1.0f + erff(x * 0.70710678118654752440f));
}

__device__ __forceinline__ unsigned to_key(float x) {
    unsigned u = __float_as_uint(x);
    return (u & 0x80000000u) ? ~u : (u | 0x80000000u);
}

// ---------------- Top-K (radix select, parallel, exact tie handling) -------
__device__ int block_scan_excl_1024(int v, int* shw) {
    int lane = threadIdx.x & 63, w = threadIdx.x >> 6;
    int x = v;
    #pragma unroll
    for (int o = 1; o < 64; o <<= 1) {
        int t = __shfl_up(x, o, 64);
        if (lane >= o) x += t;
    }
    if (lane == 63) shw[w] = x;
    __syncthreads();
    if (w == 0) {
        int y = (lane < 16) ? shw[lane] : 0;
        #pragma unroll
        for (int o = 1; o < 16; o <<= 1) {
            int t = __shfl_up(y, o, 64);
            if (lane >= o) y += t;
        }
        if (lane < 16) shw[lane] = y;
    }
    __syncthreads();
    int off = (w == 0) ? 0 : shw[w - 1];
    return off + x - v;   // exclusive prefix
}

#define TKCH 33   // ceil(GG/1024)

__global__ __launch_bounds__(1024) void topk_kernel(const float* __restrict__ expr,
                                                    int* __restrict__ idxout,
                                                    int* __restrict__ cntout) {
    __shared__ unsigned hist[16][256];
    __shared__ int shw[16];
    __shared__ unsigned sh_prefix;
    __shared__ int sh_want;
    __shared__ int sh_tot2;

    int b = blockIdx.x;
    int tid = threadIdx.x, wv = tid >> 6;
    const float* row = expr + (size_t)b * GG;

    unsigned prefix = 0;
    int want = KK;
    for (int p = 3; p >= 0; --p) {
        for (int i = tid; i < 16 * 256; i += 1024) ((unsigned*)hist)[i] = 0u;
        __syncthreads();
        int shift = p * 8;
        unsigned pmask = (p == 3) ? 0u : (0xFFFFFFFFu << (shift + 8));
        for (int i = tid; i < GG / 4; i += 1024) {         // 8384 float4 = 33536
            float4 v4 = *(const float4*)(row + 4 * i);
            float vv[4] = {v4.x, v4.y, v4.z, v4.w};
            #pragma unroll
            for (int j = 0; j < 4; ++j) {
                unsigned key = to_key(vv[j]);
                if ((key & pmask) == (prefix & pmask))
                    atomicAdd(&hist[wv][(key >> shift) & 255u], 1u);
            }
        }
        if (tid < 2) {                                      // tail 33536, 33537
            unsigned key = to_key(row[33536 + tid]);
            if ((key & pmask) == (prefix & pmask))
                atomicAdd(&hist[15][(key >> shift) & 255u], 1u);
        }
        __syncthreads();
        unsigned cnt = 0;
        if (tid < 256) {
            #pragma unroll
            for (int j = 1; j < 16; ++j) cnt += hist[j][tid];
            cnt += hist[0][tid];
            hist[0][tid] = cnt;                             // own column only
        }
        __syncthreads();
        int v = (tid < 256) ? (int)hist[0][255 - tid] : 0;  // descending bins
        int above = block_scan_excl_1024(v, shw);           // count in bins > mine
        if (tid < 256 && above < want && above + v >= want) {
            sh_prefix = prefix | ((unsigned)(255 - tid) << shift);
            sh_want = want - above;
        }
        __syncthreads();
        prefix = sh_prefix;
        want = sh_want;
        __syncthreads();
    }
    unsigned kth = prefix;

    // ordered pass over contiguous per-thread chunks (ascending index)
    int start = tid * TKCH;
    int end = min(start + TKCH, GG);
    int c_eq = 0;
    for (int g = start; g < end; ++g) c_eq += (to_key(row[g]) == kth);
    int eq_base = block_scan_excl_1024(c_eq, shw);

    int c_act = 0;
    {
        int leq = 0;
        for (int g = start; g < end; ++g) {
            float e = row[g];
            unsigned key = to_key(e);
            bool sel = (key > kth) || (key == kth && (eq_base + leq) < want);
            leq += (key == kth);
            c_act += (sel && e > 0.0f) ? 1 : 0;
        }
    }
    int out_base = block_scan_excl_1024(c_act, shw);
    if (tid == 1023) sh_tot2 = out_base + c_act;
    {
        int leq = 0, pos = out_base;
        for (int g = start; g < end; ++g) {
            float e = row[g];
            unsigned key = to_key(e);
            bool sel = (key > kth) || (key == kth && (eq_base + leq) < want);
            leq += (key == kth);
            if (sel && e > 0.0f) idxout[b * KK + pos++] = g;
        }
    }
    __syncthreads();
    if (tid == 0) cntout[b] = sh_tot2;
}

// ---------------- weight fp32 -> bf16 ----------------
__global__ __launch_bounds__(256) void cvt_bf16_kernel(const float* __restrict__ s,
                                                       ub16* __restrict__ d, int n) {
    int i = blockIdx.x * 256 + threadIdx.x;
    if (i < n) d[i] = f2b(s[i]);
}

// ---------------- Token embedding ----------------
__global__ __launch_bounds__(256) void build_h_kernel(const float* __restrict__ expr,
                                                      const int* __restrict__ idxb,
                                                      const int* __restrict__ cntb,
                                                      const float* __restrict__ ep_w1,
                                                      const float* __restrict__ ep_b1,
                                                      ub16* __restrict__ H) {
    int i = blockIdx.x * 256 + threadIdx.x;       // < BB*KK*DD
    int r = i >> 8, d = i & 255;
    int b = r >> 11, jj = r & (KK - 1);
    float v = 0.0f;
    if (jj < cntb[b]) {
        int g = idxb[b * KK + jj];
        float e = expr[(size_t)b * GG + g];
        v = gelu_f(e * ep_w1[d] + ep_b1[d]);
    }
    H[i] = f2b(v);
}

__global__ __launch_bounds__(256) void assemble_kernel(const float* __restrict__ VAL,
                                                       const float* __restrict__ gene_emb,
                                                       const float* __restrict__ clsv,
                                                       const int* __restrict__ idxb,
                                                       const int* __restrict__ cntb,
                                                       float* __restrict__ x) {
    int i = blockIdx.x * 256 + threadIdx.x;       // < BT*DD
    int r = i >> 8, d = i & 255;
    int b = r / TT, t = r % TT;
    float v;
    if (t == 0) {
        v = clsv[d];
    } else {
        int jj = t - 1;
        if (jj < cntb[b]) {
            int g = idxb[b * KK + jj];
            v = gene_emb[(size_t)g * DD + d] + VAL[((size_t)b * KK + jj) * DD + d];
        } else {
            v = 0.0f;
        }
    }
    x[i] = v;
}

// ---------------- LayerNorm: wave per row, no barriers ----------------
__global__ __launch_bounds__(256) void ln_kernel(const float* __restrict__ X,
                                                 const float* __restrict__ s,
                                                 const float* __restrict__ bsh,
                                                 ub16* __restrict__ Y16,
                                                 float* __restrict__ Yf) {
    int w = threadIdx.x >> 6, lane = threadIdx.x & 63;
    size_t r = (size_t)blockIdx.x * 4 + w;        // BT = 4*2049 exactly
    float4 xv = *(const float4*)(X + r * 256 + lane * 4);
    float sum = xv.x + xv.y + xv.z + xv.w;
    #pragma unroll
    for (int o = 1; o < 64; o <<= 1) sum += __shfl_xor(sum, o);
    float mu = sum * (1.0f / 256.0f);
    float d0 = xv.x - mu, d1 = xv.y - mu, d2 = xv.z - mu, d3 = xv.w - mu;
    float vs = d0 * d0 + d1 * d1 + d2 * d2 + d3 * d3;
    #pragma unroll
    for (int o = 1; o < 64; o <<= 1) vs += __shfl_xor(vs, o);
    float rstd = rsqrtf(vs * (1.0f / 256.0f) + 1e-5f);
    float4 sc = *(const float4*)(s + lane * 4);
    float4 bc = *(const float4*)(bsh + lane * 4);
    float y0 = d0 * rstd * sc.x + bc.x;
    float y1 = d1 * rstd * sc.y + bc.y;
    float y2 = d2 * rstd * sc.z + bc.z;
    float y3 = d3 * rstd * sc.w + bc.w;
    if (Y16) {
        uint2 o2 = make_uint2(pk2(y0, y1), pk2(y2, y3));
        *(uint2*)(Y16 + r * 256 + lane * 4) = o2;
    } else {
        *(float4*)(Yf + r * 256 + lane * 4) = make_float4(y0, y1, y2, y3);
    }
}

// ---------------- bf16 MFMA NT-GEMM, 128-row tiles ----------------
// A: M x K bf16, W: N x K bf16, C = act(A@W^T + bias)(+R). BM=128, BK=64.
// BN=128: 4 waves in 2x2, each 64x64. BN=64: 4 waves in 4x1, each 32x64.
template<int BN, int WM, int WN>
__global__ __launch_bounds__(256) void gemm128(const ub16* __restrict__ A,
                                               const ub16* __restrict__ W,
                                               const float* __restrict__ bias,
                                               const float* __restrict__ R,
                                               float* __restrict__ Cf,
                                               ub16* __restrict__ Ch,
                                               int M, int N, int K, int gelu_flag) {
    constexpr int MR = WM / 16, NR = WN / 16;
    constexpr int NWC = BN / WN;              // waves along N
    constexpr int TB = 256 / BN;              // threads per B row
    constexpr int BWT = 64 / TB;              // bf16 per thread (B row)
    __shared__ ub16 As[128][72];
    __shared__ ub16 Ws[BN][72];

    int tid = threadIdx.x;
    int lane = tid & 63, w = tid >> 6;
    int wr = (w / NWC) * WM, wc = (w % NWC) * WN;
    int bm = blockIdx.y * 128, bn = blockIdx.x * BN;
    int fr = lane & 15, fc = 8 * (lane >> 4);

    int arow = tid >> 1, ac = (tid & 1) * 32;
    int gmA = min(bm + arow, M - 1);
    const ub16* apg = A + (size_t)gmA * K + ac;
    int brow = tid / TB, bc = (tid % TB) * BWT;
    const ub16* wpg = W + (size_t)(bn + brow) * K + bc;

    f32x4 acc[MR][NR] = {};
    bf16x8 ra[4], rb[BWT / 8];
    #pragma unroll
    for (int i = 0; i < 4; ++i) ra[i] = *(const bf16x8*)(apg + i * 8);
    #pragma unroll
    for (int i = 0; i < BWT / 8; ++i) rb[i] = *(const bf16x8*)(wpg + i * 8);

    for (int k0 = 0; k0 < K; k0 += 64) {
        #pragma unroll
        for (int i = 0; i < 4; ++i) *(bf16x8*)&As[arow][ac + i * 8] = ra[i];
        #pragma unroll
        for (int i = 0; i < BWT / 8; ++i) *(bf16x8*)&Ws[brow][bc + i * 8] = rb[i];
        __syncthreads();
        if (k0 + 64 < K) {
            #pragma unroll
            for (int i = 0; i < 4; ++i) ra[i] = *(const bf16x8*)(apg + k0 + 64 + i * 8);
            #pragma unroll
            for (int i = 0; i < BWT / 8; ++i) rb[i] = *(const bf16x8*)(wpg + k0 + 64 + i * 8);
        }
        #pragma unroll
        for (int ks = 0; ks < 2; ++ks) {
            bf16x8 af[MR], bfv[NR];
            #pragma unroll
            for (int mr = 0; mr < MR; ++mr)
                af[mr] = *(const bf16x8*)&As[wr + mr * 16 + fr][ks * 32 + fc];
            #pragma unroll
            for (int nr = 0; nr < NR; ++nr)
                bfv[nr] = *(const bf16x8*)&Ws[wc + nr * 16 + fr][ks * 32 + fc];
            #pragma unroll
            for (int mr = 0; mr < MR; ++mr)
                #pragma unroll
                for (int nr = 0; nr < NR; ++nr)
                    acc[mr][nr] = __builtin_amdgcn_mfma_f32_16x16x32_bf16(
                        af[mr], bfv[nr], acc[mr][nr], 0, 0, 0);
        }
        __syncthreads();
    }

    #pragma unroll
    for (int mr = 0; mr < MR; ++mr) {
        #pragma unroll
        for (int nr = 0; nr < NR; ++nr) {
            #pragma unroll
            for (int reg = 0; reg < 4; ++reg) {
                int gm = bm + wr + mr * 16 + (lane >> 4) * 4 + reg;
                int gn = bn + wc + nr * 16 + (lane & 15);
                if (gm >= M) continue;
                float v = acc[mr][nr][reg] + bias[gn];
                if (R) v += R[(size_t)gm * N + gn];
                if (gelu_flag) v = gelu_f(v);
                if (Cf) Cf[(size_t)gm * N + gn] = v;
                else    Ch[(size_t)gm * N + gn] = f2b(v);
            }
        }
    }
}

// ---------------- K/V cache prep: dense tiled Kc + transposed Vt ----------------
__global__ __launch_bounds__(256) void kvprep(const ub16* __restrict__ qkv,
                                              ub16* __restrict__ Kc,
                                              ub16* __restrict__ Vt) {
    __shared__ unsigned vl[32][33];
    int bh = blockIdx.x, b = bh >> 3, h = bh & 7;
    int c = blockIdx.y;                 // 64-key chunk
    int tid = threadIdx.x;
    int krel = tid >> 2;                // 0..63
    int key = c * 64 + krel;
    int d8 = (tid & 3) * 8;
    U4B kv = {}, vv = {};
    if (key < TT) {
        const ub16* p = qkv + ((size_t)(b * TT + key)) * 768 + 256 + h * 32 + d8;
        kv.v = *(const bf16x8*)p;
        vv.v = *(const bf16x8*)(p + 256);
    }
    int kt = c * 2 + (krel >> 5);
    if (kt < NT)
        *(bf16x8*)(Kc + (((size_t)bh * NT + kt) * 32 + (krel & 31)) * 32 + d8) = kv.v;

    unsigned pu[4];
    #pragma unroll
    for (int j = 0; j < 4; ++j) pu[j] = __shfl_xor(vv.u[j], 4);
    if (!(krel & 1)) {
        int kp = krel >> 1;
        #pragma unroll
        for (int j = 0; j < 8; ++j) {
            unsigned mine = (vv.u[j >> 1] >> ((j & 1) * 16)) & 0xffffu;
            unsigned oth  = (pu[j >> 1] >> ((j & 1) * 16)) & 0xffffu;
            vl[d8 + j][kp] = mine | (oth << 16);
        }
    }
    __syncthreads();
    int d = tid >> 3, c8 = tid & 7;
    U4B o;
    #pragma unroll
    for (int i = 0; i < 4; ++i) o.u[i] = vl[d][c8 * 4 + i];
    int kt2 = c * 2 + (c8 >> 2);
    if (kt2 < NT)
        *(bf16x8*)(Vt + (((size_t)bh * NT + kt2) * 32 + d) * 32 + (c8 & 3) * 8) = o.v;
}

// ---------------- MFMA flash attention: no LDS staging, no barriers ----------
__global__ __launch_bounds__(256) void attn_mfma2(const ub16* __restrict__ qkv,
                                                  const ub16* __restrict__ Kc,
                                                  const ub16* __restrict__ Vt,
                                                  const int* __restrict__ cnt,
                                                  ub16* __restrict__ attno) {
    __shared__ float Olds[4][32][33];
    int bh = blockIdx.x, b = bh >> 3, h = bh & 7;
    int tid = threadIdx.x;
    int w = tid >> 6, lane = tid & 63, hi = lane >> 5, q = lane & 31;
    int qt = blockIdx.y * 4 + w;
    if (qt * 32 >= TT) return;
    int t = qt * 32 + q;
    int nvalid = cnt[b] + 1;
    int nkt = (nvalid + 31) >> 5;
    int nfull = (nvalid & 31) ? nkt - 1 : nkt;
    const float c1 = 0.17677669529663688f * 1.44269504088896340f; // scale * log2e

    int tc = min(t, TT - 1);
    const ub16* qp = qkv + ((size_t)(b * TT + tc)) * 768 + h * 32 + 8 * hi;
    bf16x8 bq0 = *(const bf16x8*)qp;
    bf16x8 bq1 = *(const bf16x8*)(qp + 16);

    float m = -1e30f, l = 0.0f;
    f32x16 ot = {};

    const ub16* kp = Kc + ((size_t)bh * NT) * 1024 + q * 32 + 8 * hi;
    const ub16* vp = Vt + ((size_t)bh * NT) * 1024 + q * 32 + 8 * hi;
    bf16x8 ka0 = *(const bf16x8*)kp;
    bf16x8 ka1 = *(const bf16x8*)(kp + 16);
    bf16x8 va0 = *(const bf16x8*)vp;
    bf16x8 va1 = *(const bf16x8*)(vp + 16);

    for (int kt = 0; kt < nkt; ++kt) {
        bf16x8 nk0 = ka0, nk1 = ka1, nv0 = va0, nv1 = va1;
        if (kt + 1 < nkt) {
            kp += 1024; vp += 1024;
            nk0 = *(const bf16x8*)kp;
            nk1 = *(const bf16x8*)(kp + 16);
            nv0 = *(const bf16x8*)vp;
            nv1 = *(const bf16x8*)(vp + 16);
        }
        f32x16 zz = {};
        f32x16 st = __builtin_amdgcn_mfma_f32_32x32x16_bf16(ka0, bq0, zz, 0, 0, 0);
        st = __builtin_amdgcn_mfma_f32_32x32x16_bf16(ka1, bq1, st, 0, 0, 0);

        #pragma unroll
        for (int r = 0; r < 16; ++r) st[r] *= c1;
        if (kt >= nfull) {
            int k0 = kt << 5;
            #pragma unroll
            for (int r = 0; r < 16; ++r) {
                int key = k0 + (r & 3) + 8 * (r >> 2) + 4 * hi;
                if (key >= nvalid) st[r] = -1e30f;
            }
        }
        float pmax = -1e30f;
        #pragma unroll
        for (int r = 0; r < 16; ++r) pmax = fmaxf(pmax, st[r]);
        pmax = fmaxf(pmax, __shfl_xor(pmax, 32));
        if (!__all(pmax <= m + 8.0f)) {
            float mnew = fmaxf(m, pmax);
            float corr = exp2f(m - mnew);
            l *= corr;
            #pragma unroll
            for (int r = 0; r < 16; ++r) ot[r] *= corr;
            m = mnew;
        }
        float tsum = 0.0f;
        #pragma unroll
        for (int r = 0; r < 16; ++r) {
            float p = exp2f(st[r] - m);
            st[r] = p;
            tsum += p;
        }
        tsum += __shfl_xor(tsum, 32);
        l += tsum;

        unsigned wd[8], sx[8];
        #pragma unroll
        for (int i = 0; i < 8; ++i) wd[i] = pk2(st[2 * i], st[2 * i + 1]);
        #pragma unroll
        for (int i = 0; i < 8; ++i) sx[i] = __shfl_xor(wd[i], 32);
        U4B p0, p1;
        if (hi == 0) {
            p0.u[0] = wd[0]; p0.u[1] = wd[1]; p0.u[2] = sx[0]; p0.u[3] = sx[1];
            p1.u[0] = wd[4]; p1.u[1] = wd[5]; p1.u[2] = sx[4]; p1.u[3] = sx[5];
        } else {
            p0.u[0] = sx[2]; p0.u[1] = sx[3]; p0.u[2] = wd[2]; p0.u[3] = wd[3];
            p1.u[0] = sx[6]; p1.u[1] = sx[7]; p1.u[2] = wd[6]; p1.u[3] = wd[7];
        }
        ot = __builtin_amdgcn_mfma_f32_32x32x16_bf16(va0, p0.v, ot, 0, 0, 0);
        ot = __builtin_amdgcn_mfma_f32_32x32x16_bf16(va1, p1.v, ot, 0, 0, 0);

        ka0 = nk0; ka1 = nk1; va0 = nv0; va1 = nv1;
    }

    float rl = 1.0f / l;
    #pragma unroll
    for (int r = 0; r < 16; ++r) {
        int d = (r & 3) + 8 * (r >> 2) + 4 * hi;
        Olds[w][q][d] = ot[r] * rl;
    }
    int row = lane >> 1, hf = lane & 1;
    int trow = qt * 32 + row;
    if (trow < TT) {
        unsigned wo[8];
        #pragma unroll
        for (int j = 0; j < 8; ++j)
            wo[j] = pk2(Olds[w][row][hf * 16 + 2 * j], Olds[w][row][hf * 16 + 2 * j + 1]);
        ub16* op = attno + ((size_t)(b * TT + trow)) * 256 + h * 32 + hf * 16;
        U4B o0, o1;
        o0.u[0] = wo[0]; o0.u[1] = wo[1]; o0.u[2] = wo[2]; o0.u[3] = wo[3];
        o1.u[0] = wo[4]; o1.u[1] = wo[5]; o1.u[2] = wo[6]; o1.u[3] = wo[7];
        *(bf16x8*)op = o0.v;
        *(bf16x8*)(op + 8) = o1.v;
    }
}

// ---------------- head ----------------
__global__ __launch_bounds__(512) void head_kernel(const float* __restrict__ Y,
                                                   const float* __restrict__ w1,
                                                   const float* __restrict__ b1,
                                                   const float* __restrict__ w2,
                                                   const float* __restrict__ b2,
                                                   float* __restrict__ out) {
    __shared__ float clsr[256];
    __shared__ float t1[512];
    int b = blockIdx.x, tid = threadIdx.x;
    if (tid < 256) clsr[tid] = Y[((size_t)b * TT) * DD + tid];
    __syncthreads();
    float acc = b1[tid];
    const float* w = w1 + (size_t)tid * 256;
    for (int k = 0; k < 256; ++k) acc += clsr[k] * w[k];
    t1[tid] = gelu_f(acc);
    __syncthreads();
    float acc2 = b2[tid];
    const float* wr = w2 + (size_t)tid * 512;
    for (int k = 0; k < 512; ++k) acc2 += t1[k] * wr[k];
    out[(size_t)b * 512 + tid] = acc2;
}

// ---------------- launch ----------------
extern "C" void kernel_launch(void* const* d_in, const int* in_sizes, int n_in,
                              void* d_out, int out_size, void* d_ws, size_t ws_size,
                              hipStream_t stream) {
    (void)in_sizes; (void)n_in; (void)out_size; (void)ws_size;
    const float* expr     = (const float*)d_in[0];
    const float* gene_emb = (const float*)d_in[1];
    const float* ep_w1    = (const float*)d_in[2];
    const float* ep_b1    = (const float*)d_in[3];
    const float* ep_w2    = (const float*)d_in[4];
    const float* ep_b2    = (const float*)d_in[5];
    const float* clsv     = (const float*)d_in[6];
    const float* ln1_s    = (const float*)d_in[7];
    const float* ln1_b    = (const float*)d_in[8];
    const float* qkv_w    = (const float*)d_in[9];
    const float* qkv_b    = (const float*)d_in[10];
    const float* out_w    = (const float*)d_in[11];
    const float* out_b    = (const float*)d_in[12];
    const float* ln2_s    = (const float*)d_in[13];
    const float* ln2_b    = (const float*)d_in[14];
    const float* ff_w1    = (const float*)d_in[15];
    const float* ff_b1    = (const float*)d_in[16];
    const float* ff_w2    = (const float*)d_in[17];
    const float* ff_b2    = (const float*)d_in[18];
    const float* fn_s     = (const float*)d_in[19];
    const float* fn_b     = (const float*)d_in[20];
    const float* pr_w1    = (const float*)d_in[21];
    const float* pr_b1    = (const float*)d_in[22];
    const float* pr_w2    = (const float*)d_in[23];
    const float* pr_b2    = (const float*)d_in[24];
    float* outp = (float*)d_out;

    const size_t KVSZ = (size_t)32 * NT * 1024;

    // workspace layout
    float* x   = (float*)d_ws;                       // BT*256 f32
    float* VAL = x + (size_t)BT * 256;               // 8192*256 f32; reused as Vt + final-LN out
    ub16* y16   = (ub16*)(VAL + (size_t)8192 * 256);
    ub16* qkv16 = y16 + (size_t)BT * 256;
    ub16* att16 = qkv16 + (size_t)BT * 768;
    ub16* ff116 = att16 + (size_t)BT * 256;
    ub16* kc_h  = ff116 + (size_t)BT * 1024;
    ub16* wqkv  = kc_h + KVSZ;
    ub16* wout  = wqkv + (size_t)LL * 768 * 256;
    ub16* wff1  = wout + (size_t)LL * 256 * 256;
    ub16* wff2  = wff1 + (size_t)LL * 1024 * 256;
    ub16* wep2  = wff2 + (size_t)LL * 256 * 1024;
    int*  idxb  = (int*)(wep2 + (size_t)256 * 256);
    int*  cntb  = idxb + BB * KK;
    ub16* H16 = kc_h;
    ub16* Kc  = kc_h;
    ub16* Vt  = (ub16*)VAL;

    // 1) top-K
    topk_kernel<<<BB, 1024, 0, stream>>>(expr, idxb, cntb);

    // 2) weights -> bf16
    cvt_bf16_kernel<<<(LL*768*256 + 255)/256, 256, 0, stream>>>(qkv_w, wqkv, LL*768*256);
    cvt_bf16_kernel<<<(LL*256*256 + 255)/256, 256, 0, stream>>>(out_w, wout, LL*256*256);
    cvt_bf16_kernel<<<(LL*1024*256 + 255)/256, 256, 0, stream>>>(ff_w1, wff1, LL*1024*256);
    cvt_bf16_kernel<<<(LL*256*1024 + 255)/256, 256, 0, stream>>>(ff_w2, wff2, LL*256*1024);
    cvt_bf16_kernel<<<(256*256 + 255)/256, 256, 0, stream>>>(ep_w2, wep2, 256*256);

    // 3) token embeddings
    build_h_kernel<<<(BB * KK * DD) / 256, 256, 0, stream>>>(expr, idxb, cntb, ep_w1, ep_b1, H16);
    gemm128<64, 32, 64><<<dim3(4, 64), 256, 0, stream>>>(H16, wep2, ep_b2, nullptr, VAL, nullptr,
                                                         8192, 256, 256, 0);
    assemble_kernel<<<BT, 256, 0, stream>>>(VAL, gene_emb, clsv, idxb, cntb, x);

    // 4) transformer layers
    for (int i = 0; i < LL; ++i) {
        ln_kernel<<<BT / 4, 256, 0, stream>>>(x, ln1_s + i * DD, ln1_b + i * DD, y16, nullptr);
        gemm128<128, 64, 64><<<dim3(6, 65), 256, 0, stream>>>(y16, wqkv + (size_t)i * 768 * 256,
                                                              qkv_b + i * 768, nullptr, nullptr, qkv16,
                                                              BT, 768, 256, 0);
        kvprep<<<dim3(BB * HH, 33), 256, 0, stream>>>(qkv16, Kc, Vt);
        attn_mfma2<<<dim3(BB * HH, 17), 256, 0, stream>>>(qkv16, Kc, Vt, cntb, att16);
        gemm128<64, 32, 64><<<dim3(4, 65), 256, 0, stream>>>(att16, wout + (size_t)i * 256 * 256,
                                                             out_b + i * 256, x, x, nullptr,
                                                             BT, 256, 256, 0);
        ln_kernel<<<BT / 4, 256, 0, stream>>>(x, ln2_s + i * DD, ln2_b + i * DD, y16, nullptr);
        gemm128<128, 64, 64><<<dim3(8, 65), 256, 0, stream>>>(y16, wff1 + (size_t)i * 1024 * 256,
                                                              ff_b1 + i * 1024, nullptr, nullptr, ff116,
                                                              BT, 1024, 256, 1);
        gemm128<64, 32, 64><<<dim3(4, 65), 256, 0, stream>>>(ff116, wff2 + (size_t)i * 256 * 1024,
                                                             ff_b2 + i * 256, x, x, nullptr,
                                                             BT, 256, 1024, 0);
    }

    // 5) final LN + head
    ln_kernel<<<BT / 4, 256, 0, stream>>>(x, fn_s, fn_b, nullptr, VAL);
    head_kernel<<<BB, 512, 0, stream>>>(VAL, pr_w1, pr_b1, pr_w2, pr_b2, outp);
}

// Round 6
// 1040.693 us; speedup vs baseline: 1.2867x; 1.2867x over previous
//
#include <hip/hip_runtime.h>
#include <hip/hip_bf16.h>
#include <math.h>

// Problem constants
#define GG 33538
#define DD 256
#define LL 6
#define HH 8
#define KK 2048
#define BB 4
#define TT 2049          // K+1 tokens
#define BT (BB*TT)       // 8196
#define NT 65            // 32-key tiles per (b,h)
#define QSC (0.17677669529663688f * 1.44269504088896340f)   // 1/sqrt(32) * log2e

typedef __bf16 bf16x8 __attribute__((ext_vector_type(8)));
typedef float f32x4 __attribute__((ext_vector_type(4)));
typedef float f32x16 __attribute__((ext_vector_type(16)));
typedef unsigned short ub16;

union BW { __bf16 h; ub16 u; };
__device__ __forceinline__ ub16 f2b(float x) { BW w; w.h = (__bf16)x; return w.u; }
__device__ __forceinline__ unsigned pk2(float a, float b) {
    return (unsigned)f2b(a) | ((unsigned)f2b(b) << 16);
}
union U4B { unsigned u[4]; bf16x8 v; };

__device__ __forceinline__ float gelu_f(float x) {
    return 0.5f * x * (1.0f + erff(x * 0.70710678118654752440f));
}

__device__ __forceinline__ unsigned to_key(float x) {
    unsigned u = __float_as_uint(x);
    return (u & 0x80000000u) ? ~u : (u | 0x80000000u);
}

// ---------------- Top-K (radix select, parallel, exact tie handling) -------
__device__ int block_scan_excl_1024(int v, int* shw) {
    int lane = threadIdx.x & 63, w = threadIdx.x >> 6;
    int x = v;
    #pragma unroll
    for (int o = 1; o < 64; o <<= 1) {
        int t = __shfl_up(x, o, 64);
        if (lane >= o) x += t;
    }
    if (lane == 63) shw[w] = x;
    __syncthreads();
    if (w == 0) {
        int y = (lane < 16) ? shw[lane] : 0;
        #pragma unroll
        for (int o = 1; o < 16; o <<= 1) {
            int t = __shfl_up(y, o, 64);
            if (lane >= o) y += t;
        }
        if (lane < 16) shw[lane] = y;
    }
    __syncthreads();
    int off = (w == 0) ? 0 : shw[w - 1];
    return off + x - v;   // exclusive prefix
}

#define TKCH 33   // ceil(GG/1024)

__global__ __launch_bounds__(1024) void topk_kernel(const float* __restrict__ expr,
                                                    int* __restrict__ idxout,
                                                    int* __restrict__ cntout) {
    __shared__ unsigned hist[16][256];
    __shared__ int shw[16];
    __shared__ unsigned sh_prefix;
    __shared__ int sh_want;
    __shared__ int sh_tot2;

    int b = blockIdx.x;
    int tid = threadIdx.x, wv = tid >> 6;
    const float* row = expr + (size_t)b * GG;

    unsigned prefix = 0;
    int want = KK;
    for (int p = 3; p >= 0; --p) {
        for (int i = tid; i < 16 * 256; i += 1024) ((unsigned*)hist)[i] = 0u;
        __syncthreads();
        int shift = p * 8;
        unsigned pmask = (p == 3) ? 0u : (0xFFFFFFFFu << (shift + 8));
        for (int i = tid; i < GG / 4; i += 1024) {
            float4 v4 = *(const float4*)(row + 4 * i);
            float vv[4] = {v4.x, v4.y, v4.z, v4.w};
            #pragma unroll
            for (int j = 0; j < 4; ++j) {
                unsigned key = to_key(vv[j]);
                if ((key & pmask) == (prefix & pmask))
                    atomicAdd(&hist[wv][(key >> shift) & 255u], 1u);
            }
        }
        if (tid < 2) {
            unsigned key = to_key(row[33536 + tid]);
            if ((key & pmask) == (prefix & pmask))
                atomicAdd(&hist[15][(key >> shift) & 255u], 1u);
        }
        __syncthreads();
        unsigned cnt = 0;
        if (tid < 256) {
            #pragma unroll
            for (int j = 1; j < 16; ++j) cnt += hist[j][tid];
            cnt += hist[0][tid];
            hist[0][tid] = cnt;
        }
        __syncthreads();
        int v = (tid < 256) ? (int)hist[0][255 - tid] : 0;
        int above = block_scan_excl_1024(v, shw);
        if (tid < 256 && above < want && above + v >= want) {
            sh_prefix = prefix | ((unsigned)(255 - tid) << shift);
            sh_want = want - above;
        }
        __syncthreads();
        prefix = sh_prefix;
        want = sh_want;
        __syncthreads();
    }
    unsigned kth = prefix;

    int start = tid * TKCH;
    int end = min(start + TKCH, GG);
    int c_eq = 0;
    for (int g = start; g < end; ++g) c_eq += (to_key(row[g]) == kth);
    int eq_base = block_scan_excl_1024(c_eq, shw);

    int c_act = 0;
    {
        int leq = 0;
        for (int g = start; g < end; ++g) {
            float e = row[g];
            unsigned key = to_key(e);
            bool sel = (key > kth) || (key == kth && (eq_base + leq) < want);
            leq += (key == kth);
            c_act += (sel && e > 0.0f) ? 1 : 0;
        }
    }
    int out_base = block_scan_excl_1024(c_act, shw);
    if (tid == 1023) sh_tot2 = out_base + c_act;
    {
        int leq = 0, pos = out_base;
        for (int g = start; g < end; ++g) {
            float e = row[g];
            unsigned key = to_key(e);
            bool sel = (key > kth) || (key == kth && (eq_base + leq) < want);
            leq += (key == kth);
            if (sel && e > 0.0f) idxout[b * KK + pos++] = g;
        }
    }
    __syncthreads();
    if (tid == 0) cntout[b] = sh_tot2;
}

// ---------------- weight fp32 -> bf16 ----------------
__global__ __launch_bounds__(256) void cvt_bf16_kernel(const float* __restrict__ s,
                                                       ub16* __restrict__ d, int n) {
    int i = blockIdx.x * 256 + threadIdx.x;
    if (i < n) d[i] = f2b(s[i]);
}

// ---------------- Token embedding ----------------
__global__ __launch_bounds__(256) void build_h_kernel(const float* __restrict__ expr,
                                                      const int* __restrict__ idxb,
                                                      const int* __restrict__ cntb,
                                                      const float* __restrict__ ep_w1,
                                                      const float* __restrict__ ep_b1,
                                                      ub16* __restrict__ H) {
    int i = blockIdx.x * 256 + threadIdx.x;       // < BB*KK*DD
    int r = i >> 8, d = i & 255;
    int b = r >> 11, jj = r & (KK - 1);
    float v = 0.0f;
    if (jj < cntb[b]) {
        int g = idxb[b * KK + jj];
        float e = expr[(size_t)b * GG + g];
        v = gelu_f(e * ep_w1[d] + ep_b1[d]);
    }
    H[i] = f2b(v);
}

__global__ __launch_bounds__(256) void assemble_kernel(const float* __restrict__ VAL,
                                                       const float* __restrict__ gene_emb,
                                                       const float* __restrict__ clsv,
                                                       const int* __restrict__ idxb,
                                                       const int* __restrict__ cntb,
                                                       float* __restrict__ x) {
    int i = blockIdx.x * 256 + threadIdx.x;       // < BT*DD
    int r = i >> 8, d = i & 255;
    int b = r / TT, t = r % TT;
    float v;
    if (t == 0) {
        v = clsv[d];
    } else {
        int jj = t - 1;
        if (jj < cntb[b]) {
            int g = idxb[b * KK + jj];
            v = gene_emb[(size_t)g * DD + d] + VAL[((size_t)b * KK + jj) * DD + d];
        } else {
            v = 0.0f;
        }
    }
    x[i] = v;
}

// ---------------- LayerNorm: wave per row, no barriers ----------------
__global__ __launch_bounds__(256) void ln_kernel(const float* __restrict__ X,
                                                 const float* __restrict__ s,
                                                 const float* __restrict__ bsh,
                                                 ub16* __restrict__ Y16,
                                                 float* __restrict__ Yf) {
    int w = threadIdx.x >> 6, lane = threadIdx.x & 63;
    size_t r = (size_t)blockIdx.x * 4 + w;        // BT = 4*2049 exactly
    float4 xv = *(const float4*)(X + r * 256 + lane * 4);
    float sum = xv.x + xv.y + xv.z + xv.w;
    #pragma unroll
    for (int o = 1; o < 64; o <<= 1) sum += __shfl_xor(sum, o);
    float mu = sum * (1.0f / 256.0f);
    float d0 = xv.x - mu, d1 = xv.y - mu, d2 = xv.z - mu, d3 = xv.w - mu;
    float vs = d0 * d0 + d1 * d1 + d2 * d2 + d3 * d3;
    #pragma unroll
    for (int o = 1; o < 64; o <<= 1) vs += __shfl_xor(vs, o);
    float rstd = rsqrtf(vs * (1.0f / 256.0f) + 1e-5f);
    float4 sc = *(const float4*)(s + lane * 4);
    float4 bc = *(const float4*)(bsh + lane * 4);
    float y0 = d0 * rstd * sc.x + bc.x;
    float y1 = d1 * rstd * sc.y + bc.y;
    float y2 = d2 * rstd * sc.z + bc.z;
    float y3 = d3 * rstd * sc.w + bc.w;
    if (Y16) {
        uint2 o2 = make_uint2(pk2(y0, y1), pk2(y2, y3));
        *(uint2*)(Y16 + r * 256 + lane * 4) = o2;
    } else {
        *(float4*)(Yf + r * 256 + lane * 4) = make_float4(y0, y1, y2, y3);
    }
}

// ---------------- bf16 MFMA NT-GEMM: C = act(A @ W^T + bias) (+R) ----------------
// A: M x K bf16, W: N x K bf16. Tile 64x64, BK=64 (2 sub-buffers), 4 waves.
// qcols>0: scale output columns [0,qcols) by QSC (Q pre-scaling for attention).
__global__ __launch_bounds__(256) void gemm_bt16(const ub16* __restrict__ A,
                                                 const ub16* __restrict__ W,
                                                 const float* __restrict__ bias,
                                                 const float* __restrict__ R,
                                                 float* __restrict__ Cf,
                                                 ub16* __restrict__ Ch,
                                                 int M, int N, int K, int gelu_flag,
                                                 int qcols) {
    __shared__ ub16 As[2][64][40];
    __shared__ ub16 Ws[2][64][40];
    int tid = threadIdx.x;
    int lane = tid & 63, w = tid >> 6;
    int wr = (w >> 1) * 32, wc = (w & 1) * 32;
    int bm = blockIdx.y * 64, bn = blockIdx.x * 64;
    f32x4 acc[2][2] = {};

    int lrow = tid >> 2, lc8 = (tid & 3) * 8;
    int arow = min(bm + lrow, M - 1);
    const ub16* ap = A + (size_t)arow * K + lc8;
    const ub16* wp = W + (size_t)(bn + lrow) * K + lc8;

    int fr = lane & 15, fc = 8 * (lane >> 4);
    for (int k0 = 0; k0 < K; k0 += 64) {
        bf16x8 av0 = *(const bf16x8*)(ap + k0);
        bf16x8 av1 = *(const bf16x8*)(ap + k0 + 32);
        bf16x8 wv0 = *(const bf16x8*)(wp + k0);
        bf16x8 wv1 = *(const bf16x8*)(wp + k0 + 32);
        *(bf16x8*)&As[0][lrow][lc8] = av0;
        *(bf16x8*)&As[1][lrow][lc8] = av1;
        *(bf16x8*)&Ws[0][lrow][lc8] = wv0;
        *(bf16x8*)&Ws[1][lrow][lc8] = wv1;
        __syncthreads();
        #pragma unroll
        for (int ks = 0; ks < 2; ++ks) {
            bf16x8 a0 = *(const bf16x8*)&As[ks][wr + fr][fc];
            bf16x8 a1 = *(const bf16x8*)&As[ks][wr + 16 + fr][fc];
            bf16x8 b0 = *(const bf16x8*)&Ws[ks][wc + fr][fc];
            bf16x8 b1 = *(const bf16x8*)&Ws[ks][wc + 16 + fr][fc];
            acc[0][0] = __builtin_amdgcn_mfma_f32_16x16x32_bf16(a0, b0, acc[0][0], 0, 0, 0);
            acc[0][1] = __builtin_amdgcn_mfma_f32_16x16x32_bf16(a0, b1, acc[0][1], 0, 0, 0);
            acc[1][0] = __builtin_amdgcn_mfma_f32_16x16x32_bf16(a1, b0, acc[1][0], 0, 0, 0);
            acc[1][1] = __builtin_amdgcn_mfma_f32_16x16x32_bf16(a1, b1, acc[1][1], 0, 0, 0);
        }
        __syncthreads();
    }

    #pragma unroll
    for (int i = 0; i < 2; ++i) {
        #pragma unroll
        for (int j = 0; j < 2; ++j) {
            #pragma unroll
            for (int reg = 0; reg < 4; ++reg) {
                int gm = bm + wr + i * 16 + (lane >> 4) * 4 + reg;
                int gn = bn + wc + j * 16 + (lane & 15);
                if (gm >= M) continue;
                float v = acc[i][j][reg] + bias[gn];
                if (R) v += R[(size_t)gm * N + gn];
                if (gelu_flag) v = gelu_f(v);
                if (gn < qcols) v *= QSC;
                if (Cf) Cf[(size_t)gm * N + gn] = v;
                else    Ch[(size_t)gm * N + gn] = f2b(v);
            }
        }
    }
}

// ---------------- K/V cache prep: dense tiled Kc + transposed Vt ----------------
__global__ __launch_bounds__(256) void kvprep(const ub16* __restrict__ qkv,
                                              ub16* __restrict__ Kc,
                                              ub16* __restrict__ Vt) {
    __shared__ unsigned vl[32][33];
    int bh = blockIdx.x, b = bh >> 3, h = bh & 7;
    int c = blockIdx.y;                 // 64-key chunk
    int tid = threadIdx.x;
    int krel = tid >> 2;                // 0..63
    int key = c * 64 + krel;
    int d8 = (tid & 3) * 8;
    U4B kv = {}, vv = {};
    if (key < TT) {
        const ub16* p = qkv + ((size_t)(b * TT + key)) * 768 + 256 + h * 32 + d8;
        kv.v = *(const bf16x8*)p;
        vv.v = *(const bf16x8*)(p + 256);
    }
    int kt = c * 2 + (krel >> 5);
    if (kt < NT)
        *(bf16x8*)(Kc + (((size_t)bh * NT + kt) * 32 + (krel & 31)) * 32 + d8) = kv.v;

    unsigned pu[4];
    #pragma unroll
    for (int j = 0; j < 4; ++j) pu[j] = __shfl_xor(vv.u[j], 4);
    if (!(krel & 1)) {
        int kp = krel >> 1;
        #pragma unroll
        for (int j = 0; j < 8; ++j) {
            unsigned mine = (vv.u[j >> 1] >> ((j & 1) * 16)) & 0xffffu;
            unsigned oth  = (pu[j >> 1] >> ((j & 1) * 16)) & 0xffffu;
            vl[d8 + j][kp] = mine | (oth << 16);
        }
    }
    __syncthreads();
    int d = tid >> 3, c8 = tid & 7;
    U4B o;
    #pragma unroll
    for (int i = 0; i < 4; ++i) o.u[i] = vl[d][c8 * 4 + i];
    int kt2 = c * 2 + (c8 >> 2);
    if (kt2 < NT)
        *(bf16x8*)(Vt + (((size_t)bh * NT + kt2) * 32 + d) * 32 + (c8 & 3) * 8) = o.v;
}

// ---------------- MFMA flash attention, split-K over 4 waves ----------------
// grid (B*H, 65); block 256 = 4 waves; all 4 waves share ONE 32-query tile,
// each handles every-4th key tile; partials merged in LDS.
__global__ __launch_bounds__(256) void attn_mfma3(const ub16* __restrict__ qkv,
                                                  const ub16* __restrict__ Kc,
                                                  const ub16* __restrict__ Vt,
                                                  const int* __restrict__ cnt,
                                                  ub16* __restrict__ attno) {
    __shared__ float Olds[4][32][33];
    __shared__ float Oml[4][32], Oll[4][32];
    int bh = blockIdx.x, b = bh >> 3, h = bh & 7;
    int tid = threadIdx.x;
    int w = tid >> 6, lane = tid & 63, hi = lane >> 5, q = lane & 31;
    int qt = blockIdx.y;
    int t = qt * 32 + q;
    int nvalid = cnt[b] + 1;
    int nkt = (nvalid + 31) >> 5;
    int nfull = (nvalid & 31) ? nkt - 1 : nkt;

    int tc = min(t, TT - 1);
    const ub16* qp = qkv + ((size_t)(b * TT + tc)) * 768 + h * 32 + 8 * hi;
    bf16x8 bq0 = *(const bf16x8*)qp;        // Q pre-scaled by QSC in gemm epilogue
    bf16x8 bq1 = *(const bf16x8*)(qp + 16);

    float m = -1e30f, l = 0.0f;
    f32x16 ot = {};

    const ub16* kp = Kc + ((size_t)bh * NT + w) * 1024 + q * 32 + 8 * hi;
    const ub16* vp = Vt + ((size_t)bh * NT + w) * 1024 + q * 32 + 8 * hi;
    bf16x8 ka0 = *(const bf16x8*)kp;
    bf16x8 ka1 = *(const bf16x8*)(kp + 16);
    bf16x8 va0 = *(const bf16x8*)vp;
    bf16x8 va1 = *(const bf16x8*)(vp + 16);

    for (int kt = w; kt < nkt; kt += 4) {
        bf16x8 nk0 = ka0, nk1 = ka1, nv0 = va0, nv1 = va1;
        if (kt + 4 < nkt) {
            kp += 4096; vp += 4096;
            nk0 = *(const bf16x8*)kp;
            nk1 = *(const bf16x8*)(kp + 16);
            nv0 = *(const bf16x8*)vp;
            nv1 = *(const bf16x8*)(vp + 16);
        }
        f32x16 zz = {};
        f32x16 st = __builtin_amdgcn_mfma_f32_32x32x16_bf16(ka0, bq0, zz, 0, 0, 0);
        st = __builtin_amdgcn_mfma_f32_32x32x16_bf16(ka1, bq1, st, 0, 0, 0);

        if (kt >= nfull) {
            int k0 = kt << 5;
            #pragma unroll
            for (int r = 0; r < 16; ++r) {
                int key = k0 + (r & 3) + 8 * (r >> 2) + 4 * hi;
                if (key >= nvalid) st[r] = -1e30f;
            }
        }
        float pmax = -1e30f;
        #pragma unroll
        for (int r = 0; r < 16; ++r) pmax = fmaxf(pmax, st[r]);
        pmax = fmaxf(pmax, __shfl_xor(pmax, 32));
        if (!__all(pmax <= m + 8.0f)) {
            float mnew = fmaxf(m, pmax);
            float corr = exp2f(m - mnew);
            l *= corr;
            #pragma unroll
            for (int r = 0; r < 16; ++r) ot[r] *= corr;
            m = mnew;
        }
        float tsum = 0.0f;
        #pragma unroll
        for (int r = 0; r < 16; ++r) {
            float p = exp2f(st[r] - m);
            st[r] = p;
            tsum += p;
        }
        tsum += __shfl_xor(tsum, 32);
        l += tsum;

        unsigned wd[8], sx[8];
        #pragma unroll
        for (int i = 0; i < 8; ++i) wd[i] = pk2(st[2 * i], st[2 * i + 1]);
        #pragma unroll
        for (int i = 0; i < 8; ++i) sx[i] = __shfl_xor(wd[i], 32);
        U4B p0, p1;
        if (hi == 0) {
            p0.u[0] = wd[0]; p0.u[1] = wd[1]; p0.u[2] = sx[0]; p0.u[3] = sx[1];
            p1.u[0] = wd[4]; p1.u[1] = wd[5]; p1.u[2] = sx[4]; p1.u[3] = sx[5];
        } else {
            p0.u[0] = sx[2]; p0.u[1] = sx[3]; p0.u[2] = wd[2]; p0.u[3] = wd[3];
            p1.u[0] = sx[6]; p1.u[1] = sx[7]; p1.u[2] = wd[6]; p1.u[3] = wd[7];
        }
        ot = __builtin_amdgcn_mfma_f32_32x32x16_bf16(va0, p0.v, ot, 0, 0, 0);
        ot = __builtin_amdgcn_mfma_f32_32x32x16_bf16(va1, p1.v, ot, 0, 0, 0);

        ka0 = nk0; ka1 = nk1; va0 = nv0; va1 = nv1;
    }

    // deposit per-wave partials (unnormalized)
    #pragma unroll
    for (int r = 0; r < 16; ++r) {
        int d = (r & 3) + 8 * (r >> 2) + 4 * hi;
        Olds[w][q][d] = ot[r];
    }
    if (hi == 0) { Oml[w][q] = m; Oll[w][q] = l; }
    __syncthreads();

    // merge: thread -> (q row, 4-wide d group)
    int qq = tid >> 3, dg = tid & 7;
    int trow = qt * 32 + qq;
    if (trow < TT) {
        float m0 = Oml[0][qq], m1 = Oml[1][qq], m2 = Oml[2][qq], m3 = Oml[3][qq];
        float M = fmaxf(fmaxf(m0, m1), fmaxf(m2, m3));
        float s0 = exp2f(m0 - M), s1 = exp2f(m1 - M);
        float s2 = exp2f(m2 - M), s3 = exp2f(m3 - M);
        float L = s0 * Oll[0][qq] + s1 * Oll[1][qq] + s2 * Oll[2][qq] + s3 * Oll[3][qq];
        float rL = 1.0f / L;
        float o[4];
        #pragma unroll
        for (int j = 0; j < 4; ++j) {
            int d = dg * 4 + j;
            o[j] = (s0 * Olds[0][qq][d] + s1 * Olds[1][qq][d] +
                    s2 * Olds[2][qq][d] + s3 * Olds[3][qq][d]) * rL;
        }
        uint2 o2 = make_uint2(pk2(o[0], o[1]), pk2(o[2], o[3]));
        *(uint2*)(attno + ((size_t)(b * TT + trow)) * 256 + h * 32 + dg * 4) = o2;
    }
}

// ---------------- head ----------------
__global__ __launch_bounds__(512) void head_kernel(const float* __restrict__ Y,
                                                   const float* __restrict__ w1,
                                                   const float* __restrict__ b1,
                                                   const float* __restrict__ w2,
                                                   const float* __restrict__ b2,
                                                   float* __restrict__ out) {
    __shared__ float clsr[256];
    __shared__ float t1[512];
    int b = blockIdx.x, tid = threadIdx.x;
    if (tid < 256) clsr[tid] = Y[((size_t)b * TT) * DD + tid];
    __syncthreads();
    float acc = b1[tid];
    const float* w = w1 + (size_t)tid * 256;
    for (int k = 0; k < 256; ++k) acc += clsr[k] * w[k];
    t1[tid] = gelu_f(acc);
    __syncthreads();
    float acc2 = b2[tid];
    const float* wr = w2 + (size_t)tid * 512;
    for (int k = 0; k < 512; ++k) acc2 += t1[k] * wr[k];
    out[(size_t)b * 512 + tid] = acc2;
}

// ---------------- launch ----------------
extern "C" void kernel_launch(void* const* d_in, const int* in_sizes, int n_in,
                              void* d_out, int out_size, void* d_ws, size_t ws_size,
                              hipStream_t stream) {
    (void)in_sizes; (void)n_in; (void)out_size; (void)ws_size;
    const float* expr     = (const float*)d_in[0];
    const float* gene_emb = (const float*)d_in[1];
    const float* ep_w1    = (const float*)d_in[2];
    const float* ep_b1    = (const float*)d_in[3];
    const float* ep_w2    = (const float*)d_in[4];
    const float* ep_b2    = (const float*)d_in[5];
    const float* clsv     = (const float*)d_in[6];
    const float* ln1_s    = (const float*)d_in[7];
    const float* ln1_b    = (const float*)d_in[8];
    const float* qkv_w    = (const float*)d_in[9];
    const float* qkv_b    = (const float*)d_in[10];
    const float* out_w    = (const float*)d_in[11];
    const float* out_b    = (const float*)d_in[12];
    const float* ln2_s    = (const float*)d_in[13];
    const float* ln2_b    = (const float*)d_in[14];
    const float* ff_w1    = (const float*)d_in[15];
    const float* ff_b1    = (const float*)d_in[16];
    const float* ff_w2    = (const float*)d_in[17];
    const float* ff_b2    = (const float*)d_in[18];
    const float* fn_s     = (const float*)d_in[19];
    const float* fn_b     = (const float*)d_in[20];
    const float* pr_w1    = (const float*)d_in[21];
    const float* pr_b1    = (const float*)d_in[22];
    const float* pr_w2    = (const float*)d_in[23];
    const float* pr_b2    = (const float*)d_in[24];
    float* outp = (float*)d_out;

    const size_t KVSZ = (size_t)32 * NT * 1024;

    // workspace layout
    float* x   = (float*)d_ws;                       // BT*256 f32
    float* VAL = x + (size_t)BT * 256;               // 8192*256 f32; reused as Vt + final-LN out
    ub16* y16   = (ub16*)(VAL + (size_t)8192 * 256);
    ub16* qkv16 = y16 + (size_t)BT * 256;
    ub16* att16 = qkv16 + (size_t)BT * 768;
    ub16* ff116 = att16 + (size_t)BT * 256;
    ub16* kc_h  = ff116 + (size_t)BT * 1024;
    ub16* wqkv  = kc_h + KVSZ;
    ub16* wout  = wqkv + (size_t)LL * 768 * 256;
    ub16* wff1  = wout + (size_t)LL * 256 * 256;
    ub16* wff2  = wff1 + (size_t)LL * 1024 * 256;
    ub16* wep2  = wff2 + (size_t)LL * 256 * 1024;
    int*  idxb  = (int*)(wep2 + (size_t)256 * 256);
    int*  cntb  = idxb + BB * KK;
    ub16* H16 = kc_h;
    ub16* Kc  = kc_h;
    ub16* Vt  = (ub16*)VAL;

    // 1) top-K
    topk_kernel<<<BB, 1024, 0, stream>>>(expr, idxb, cntb);

    // 2) weights -> bf16
    cvt_bf16_kernel<<<(LL*768*256 + 255)/256, 256, 0, stream>>>(qkv_w, wqkv, LL*768*256);
    cvt_bf16_kernel<<<(LL*256*256 + 255)/256, 256, 0, stream>>>(out_w, wout, LL*256*256);
    cvt_bf16_kernel<<<(LL*1024*256 + 255)/256, 256, 0, stream>>>(ff_w1, wff1, LL*1024*256);
    cvt_bf16_kernel<<<(LL*256*1024 + 255)/256, 256, 0, stream>>>(ff_w2, wff2, LL*256*1024);
    cvt_bf16_kernel<<<(256*256 + 255)/256, 256, 0, stream>>>(ep_w2, wep2, 256*256);

    // 3) token embeddings
    build_h_kernel<<<(BB * KK * DD) / 256, 256, 0, stream>>>(expr, idxb, cntb, ep_w1, ep_b1, H16);
    gemm_bt16<<<dim3(4, 128), 256, 0, stream>>>(H16, wep2, ep_b2, nullptr, VAL, nullptr,
                                                8192, 256, 256, 0, 0);
    assemble_kernel<<<BT, 256, 0, stream>>>(VAL, gene_emb, clsv, idxb, cntb, x);

    // 4) transformer layers
    for (int i = 0; i < LL; ++i) {
        ln_kernel<<<BT / 4, 256, 0, stream>>>(x, ln1_s + i * DD, ln1_b + i * DD, y16, nullptr);
        gemm_bt16<<<dim3(12, 129), 256, 0, stream>>>(y16, wqkv + (size_t)i * 768 * 256,
                                                     qkv_b + i * 768, nullptr, nullptr, qkv16,
                                                     BT, 768, 256, 0, 256);
        kvprep<<<dim3(BB * HH, 33), 256, 0, stream>>>(qkv16, Kc, Vt);
        attn_mfma3<<<dim3(BB * HH, NT), 256, 0, stream>>>(qkv16, Kc, Vt, cntb, att16);
        gemm_bt16<<<dim3(4, 129), 256, 0, stream>>>(att16, wout + (size_t)i * 256 * 256,
                                                    out_b + i * 256, x, x, nullptr,
                                                    BT, 256, 256, 0, 0);
        ln_kernel<<<BT / 4, 256, 0, stream>>>(x, ln2_s + i * DD, ln2_b + i * DD, y16, nullptr);
        gemm_bt16<<<dim3(16, 129), 256, 0, stream>>>(y16, wff1 + (size_t)i * 1024 * 256,
                                                     ff_b1 + i * 1024, nullptr, nullptr, ff116,
                                                     BT, 1024, 256, 1, 0);
        gemm_bt16<<<dim3(4, 129), 256, 0, stream>>>(ff116, wff2 + (size_t)i * 256 * 1024,
                                                    ff_b2 + i * 256, x, x, nullptr,
                                                    BT, 256, 1024, 0, 0);
    }

    // 5) final LN + head
    ln_kernel<<<BT / 4, 256, 0, stream>>>(x, fn_s, fn_b, nullptr, VAL);
    head_kernel<<<BB, 512, 0, stream>>>(VAL, pr_w1, pr_b1, pr_w2, pr_b2, outp);
}

// Round 7
// 1013.900 us; speedup vs baseline: 1.3207x; 1.0264x over previous
//
#include <hip/hip_runtime.h>
#include <hip/hip_bf16.h>
#include <math.h>

// Problem constants
#define GG 33538
#define DD 256
#define LL 6
#define HH 8
#define KK 2048
#define BB 4
#define TT 2049          // K+1 tokens
#define BT (BB*TT)       // 8196
#define NT 65            // 32-key tiles per (b,h)
#define QSC (0.17677669529663688f * 1.44269504088896340f)   // 1/sqrt(32) * log2e

typedef __bf16 bf16x8 __attribute__((ext_vector_type(8)));
typedef float f32x4 __attribute__((ext_vector_type(4)));
typedef float f32x16 __attribute__((ext_vector_type(16)));
typedef unsigned short ub16;

union BW { __bf16 h; ub16 u; };
__device__ __forceinline__ ub16 f2b(float x) { BW w; w.h = (__bf16)x; return w.u; }
__device__ __forceinline__ unsigned pk2(float a, float b) {
    return (unsigned)f2b(a) | ((unsigned)f2b(b) << 16);
}
union U4B { unsigned u[4]; bf16x8 v; };

__device__ __forceinline__ float gelu_f(float x) {
    return 0.5f * x * (1.0f + erff(x * 0.70710678118654752440f));
}

__device__ __forceinline__ unsigned to_key(float x) {
    unsigned u = __float_as_uint(x);
    return (u & 0x80000000u) ? ~u : (u | 0x80000000u);
}

// ---------------- Top-K (radix select, parallel, exact tie handling) -------
__device__ int block_scan_excl_1024(int v, int* shw) {
    int lane = threadIdx.x & 63, w = threadIdx.x >> 6;
    int x = v;
    #pragma unroll
    for (int o = 1; o < 64; o <<= 1) {
        int t = __shfl_up(x, o, 64);
        if (lane >= o) x += t;
    }
    if (lane == 63) shw[w] = x;
    __syncthreads();
    if (w == 0) {
        int y = (lane < 16) ? shw[lane] : 0;
        #pragma unroll
        for (int o = 1; o < 16; o <<= 1) {
            int t = __shfl_up(y, o, 64);
            if (lane >= o) y += t;
        }
        if (lane < 16) shw[lane] = y;
    }
    __syncthreads();
    int off = (w == 0) ? 0 : shw[w - 1];
    return off + x - v;   // exclusive prefix
}

#define TKCH 33   // ceil(GG/1024)

__global__ __launch_bounds__(1024) void topk_kernel(const float* __restrict__ expr,
                                                    int* __restrict__ idxout,
                                                    int* __restrict__ cntout) {
    __shared__ unsigned hist[16][256];
    __shared__ int shw[16];
    __shared__ unsigned sh_prefix;
    __shared__ int sh_want;
    __shared__ int sh_tot2;

    int b = blockIdx.x;
    int tid = threadIdx.x, wv = tid >> 6;
    const float* row = expr + (size_t)b * GG;

    unsigned prefix = 0;
    int want = KK;
    for (int p = 3; p >= 0; --p) {
        for (int i = tid; i < 16 * 256; i += 1024) ((unsigned*)hist)[i] = 0u;
        __syncthreads();
        int shift = p * 8;
        unsigned pmask = (p == 3) ? 0u : (0xFFFFFFFFu << (shift + 8));
        for (int i = tid; i < GG / 4; i += 1024) {
            float4 v4 = *(const float4*)(row + 4 * i);
            float vv[4] = {v4.x, v4.y, v4.z, v4.w};
            #pragma unroll
            for (int j = 0; j < 4; ++j) {
                unsigned key = to_key(vv[j]);
                if ((key & pmask) == (prefix & pmask))
                    atomicAdd(&hist[wv][(key >> shift) & 255u], 1u);
            }
        }
        if (tid < 2) {
            unsigned key = to_key(row[33536 + tid]);
            if ((key & pmask) == (prefix & pmask))
                atomicAdd(&hist[15][(key >> shift) & 255u], 1u);
        }
        __syncthreads();
        unsigned cnt = 0;
        if (tid < 256) {
            #pragma unroll
            for (int j = 1; j < 16; ++j) cnt += hist[j][tid];
            cnt += hist[0][tid];
            hist[0][tid] = cnt;
        }
        __syncthreads();
        int v = (tid < 256) ? (int)hist[0][255 - tid] : 0;
        int above = block_scan_excl_1024(v, shw);
        if (tid < 256 && above < want && above + v >= want) {
            sh_prefix = prefix | ((unsigned)(255 - tid) << shift);
            sh_want = want - above;
        }
        __syncthreads();
        prefix = sh_prefix;
        want = sh_want;
        __syncthreads();
    }
    unsigned kth = prefix;

    int start = tid * TKCH;
    int end = min(start + TKCH, GG);
    int c_eq = 0;
    for (int g = start; g < end; ++g) c_eq += (to_key(row[g]) == kth);
    int eq_base = block_scan_excl_1024(c_eq, shw);

    int c_act = 0;
    {
        int leq = 0;
        for (int g = start; g < end; ++g) {
            float e = row[g];
            unsigned key = to_key(e);
            bool sel = (key > kth) || (key == kth && (eq_base + leq) < want);
            leq += (key == kth);
            c_act += (sel && e > 0.0f) ? 1 : 0;
        }
    }
    int out_base = block_scan_excl_1024(c_act, shw);
    if (tid == 1023) sh_tot2 = out_base + c_act;
    {
        int leq = 0, pos = out_base;
        for (int g = start; g < end; ++g) {
            float e = row[g];
            unsigned key = to_key(e);
            bool sel = (key > kth) || (key == kth && (eq_base + leq) < want);
            leq += (key == kth);
            if (sel && e > 0.0f) idxout[b * KK + pos++] = g;
        }
    }
    __syncthreads();
    if (tid == 0) cntout[b] = sh_tot2;
}

// ---------------- weight fp32 -> bf16 ----------------
__global__ __launch_bounds__(256) void cvt_bf16_kernel(const float* __restrict__ s,
                                                       ub16* __restrict__ d, int n) {
    int i = blockIdx.x * 256 + threadIdx.x;
    if (i < n) d[i] = f2b(s[i]);
}

// ---------------- Token embedding ----------------
__global__ __launch_bounds__(256) void build_h_kernel(const float* __restrict__ expr,
                                                      const int* __restrict__ idxb,
                                                      const int* __restrict__ cntb,
                                                      const float* __restrict__ ep_w1,
                                                      const float* __restrict__ ep_b1,
                                                      ub16* __restrict__ H) {
    int i = blockIdx.x * 256 + threadIdx.x;       // < BB*KK*DD
    int r = i >> 8, d = i & 255;
    int b = r >> 11, jj = r & (KK - 1);
    float v = 0.0f;
    if (jj < cntb[b]) {
        int g = idxb[b * KK + jj];
        float e = expr[(size_t)b * GG + g];
        v = gelu_f(e * ep_w1[d] + ep_b1[d]);
    }
    H[i] = f2b(v);
}

__global__ __launch_bounds__(256) void assemble_kernel(const float* __restrict__ VAL,
                                                       const float* __restrict__ gene_emb,
                                                       const float* __restrict__ clsv,
                                                       const int* __restrict__ idxb,
                                                       const int* __restrict__ cntb,
                                                       float* __restrict__ x) {
    int i = blockIdx.x * 256 + threadIdx.x;       // < BT*DD
    int r = i >> 8, d = i & 255;
    int b = r / TT, t = r % TT;
    float v;
    if (t == 0) {
        v = clsv[d];
    } else {
        int jj = t - 1;
        if (jj < cntb[b]) {
            int g = idxb[b * KK + jj];
            v = gene_emb[(size_t)g * DD + d] + VAL[((size_t)b * KK + jj) * DD + d];
        } else {
            v = 0.0f;
        }
    }
    x[i] = v;
}

// ---------------- LayerNorm: wave per row, no barriers ----------------
__global__ __launch_bounds__(256) void ln_kernel(const float* __restrict__ X,
                                                 const float* __restrict__ s,
                                                 const float* __restrict__ bsh,
                                                 ub16* __restrict__ Y16,
                                                 float* __restrict__ Yf) {
    int w = threadIdx.x >> 6, lane = threadIdx.x & 63;
    size_t r = (size_t)blockIdx.x * 4 + w;        // BT = 4*2049 exactly
    float4 xv = *(const float4*)(X + r * 256 + lane * 4);
    float sum = xv.x + xv.y + xv.z + xv.w;
    #pragma unroll
    for (int o = 1; o < 64; o <<= 1) sum += __shfl_xor(sum, o);
    float mu = sum * (1.0f / 256.0f);
    float d0 = xv.x - mu, d1 = xv.y - mu, d2 = xv.z - mu, d3 = xv.w - mu;
    float vs = d0 * d0 + d1 * d1 + d2 * d2 + d3 * d3;
    #pragma unroll
    for (int o = 1; o < 64; o <<= 1) vs += __shfl_xor(vs, o);
    float rstd = rsqrtf(vs * (1.0f / 256.0f) + 1e-5f);
    float4 sc = *(const float4*)(s + lane * 4);
    float4 bc = *(const float4*)(bsh + lane * 4);
    float y0 = d0 * rstd * sc.x + bc.x;
    float y1 = d1 * rstd * sc.y + bc.y;
    float y2 = d2 * rstd * sc.z + bc.z;
    float y3 = d3 * rstd * sc.w + bc.w;
    if (Y16) {
        uint2 o2 = make_uint2(pk2(y0, y1), pk2(y2, y3));
        *(uint2*)(Y16 + r * 256 + lane * 4) = o2;
    } else {
        *(float4*)(Yf + r * 256 + lane * 4) = make_float4(y0, y1, y2, y3);
    }
}

// ---------------- bf16 MFMA NT-GEMM: C = act(A @ W^T + bias) (+R) ----------------
// A: M x K bf16, W: N x K bf16. Tile 64x64, BK=64 (2 sub-buffers), 4 waves.
// qcols>0: scale output columns [0,qcols) by QSC (Q pre-scaling for attention).
__global__ __launch_bounds__(256) void gemm_bt16(const ub16* __restrict__ A,
                                                 const ub16* __restrict__ W,
                                                 const float* __restrict__ bias,
                                                 const float* __restrict__ R,
                                                 float* __restrict__ Cf,
                                                 ub16* __restrict__ Ch,
                                                 int M, int N, int K, int gelu_flag,
                                                 int qcols) {
    __shared__ ub16 As[2][64][40];
    __shared__ ub16 Ws[2][64][40];
    int tid = threadIdx.x;
    int lane = tid & 63, w = tid >> 6;
    int wr = (w >> 1) * 32, wc = (w & 1) * 32;
    int bm = blockIdx.y * 64, bn = blockIdx.x * 64;
    f32x4 acc[2][2] = {};

    int lrow = tid >> 2, lc8 = (tid & 3) * 8;
    int arow = min(bm + lrow, M - 1);
    const ub16* ap = A + (size_t)arow * K + lc8;
    const ub16* wp = W + (size_t)(bn + lrow) * K + lc8;

    int fr = lane & 15, fc = 8 * (lane >> 4);
    for (int k0 = 0; k0 < K; k0 += 64) {
        bf16x8 av0 = *(const bf16x8*)(ap + k0);
        bf16x8 av1 = *(const bf16x8*)(ap + k0 + 32);
        bf16x8 wv0 = *(const bf16x8*)(wp + k0);
        bf16x8 wv1 = *(const bf16x8*)(wp + k0 + 32);
        *(bf16x8*)&As[0][lrow][lc8] = av0;
        *(bf16x8*)&As[1][lrow][lc8] = av1;
        *(bf16x8*)&Ws[0][lrow][lc8] = wv0;
        *(bf16x8*)&Ws[1][lrow][lc8] = wv1;
        __syncthreads();
        #pragma unroll
        for (int ks = 0; ks < 2; ++ks) {
            bf16x8 a0 = *(const bf16x8*)&As[ks][wr + fr][fc];
            bf16x8 a1 = *(const bf16x8*)&As[ks][wr + 16 + fr][fc];
            bf16x8 b0 = *(const bf16x8*)&Ws[ks][wc + fr][fc];
            bf16x8 b1 = *(const bf16x8*)&Ws[ks][wc + 16 + fr][fc];
            acc[0][0] = __builtin_amdgcn_mfma_f32_16x16x32_bf16(a0, b0, acc[0][0], 0, 0, 0);
            acc[0][1] = __builtin_amdgcn_mfma_f32_16x16x32_bf16(a0, b1, acc[0][1], 0, 0, 0);
            acc[1][0] = __builtin_amdgcn_mfma_f32_16x16x32_bf16(a1, b0, acc[1][0], 0, 0, 0);
            acc[1][1] = __builtin_amdgcn_mfma_f32_16x16x32_bf16(a1, b1, acc[1][1], 0, 0, 0);
        }
        __syncthreads();
    }

    #pragma unroll
    for (int i = 0; i < 2; ++i) {
        #pragma unroll
        for (int j = 0; j < 2; ++j) {
            #pragma unroll
            for (int reg = 0; reg < 4; ++reg) {
                int gm = bm + wr + i * 16 + (lane >> 4) * 4 + reg;
                int gn = bn + wc + j * 16 + (lane & 15);
                if (gm >= M) continue;
                float v = acc[i][j][reg] + bias[gn];
                if (R) v += R[(size_t)gm * N + gn];
                if (gelu_flag) v = gelu_f(v);
                if (gn < qcols) v *= QSC;
                if (Cf) Cf[(size_t)gm * N + gn] = v;
                else    Ch[(size_t)gm * N + gn] = f2b(v);
            }
        }
    }
}

// ---------------- K/V cache prep: dense tiled Kc + k-permuted transposed Vt ----
// Kc[bh][tile][key32][d32]; Vt[bh][tile][d32][pos32] where key k sits at
// pos = (k&3)|((k&4)<<1)|((k&8)>>1)|(k&16)  (matches S^T lane-local key order,
// so the attention P-fragment needs NO cross-lane shuffles).
__global__ __launch_bounds__(256) void kvprep(const ub16* __restrict__ qkv,
                                              ub16* __restrict__ Kc,
                                              ub16* __restrict__ Vt) {
    __shared__ unsigned vl[32][33];
    int bh = blockIdx.x, b = bh >> 3, h = bh & 7;
    int c = blockIdx.y;                 // 64-key chunk
    int tid = threadIdx.x;
    int krel = tid >> 2;                // 0..63
    int key = c * 64 + krel;
    int d8 = (tid & 3) * 8;
    U4B kv = {}, vv = {};
    if (key < TT) {
        const ub16* p = qkv + ((size_t)(b * TT + key)) * 768 + 256 + h * 32 + d8;
        kv.v = *(const bf16x8*)p;
        vv.v = *(const bf16x8*)(p + 256);
    }
    int kt = c * 2 + (krel >> 5);
    if (kt < NT)
        *(bf16x8*)(Kc + (((size_t)bh * NT + kt) * 32 + (krel & 31)) * 32 + d8) = kv.v;

    unsigned pu[4];
    #pragma unroll
    for (int j = 0; j < 4; ++j) pu[j] = __shfl_xor(vv.u[j], 4);
    if (!(krel & 1)) {
        int kp = krel >> 1;
        #pragma unroll
        for (int j = 0; j < 8; ++j) {
            unsigned mine = (vv.u[j >> 1] >> ((j & 1) * 16)) & 0xffffu;
            unsigned oth  = (pu[j >> 1] >> ((j & 1) * 16)) & 0xffffu;
            vl[d8 + j][kp] = mine | (oth << 16);
        }
    }
    __syncthreads();
    int d = tid >> 3, c8 = tid & 7;
    int kt2 = c * 2 + (c8 >> 2);
    if (kt2 < NT) {
        unsigned* vdst = (unsigned*)(Vt + (((size_t)bh * NT + kt2) * 32 + d) * 32);
        #pragma unroll
        for (int ih = 0; ih < 2; ++ih) {
            int pkr = (c8 & 3) * 4 + ih * 2;     // key-pair index 0..15 (even)
            int dp = (pkr & 1) | ((pkr & 2) << 1) | ((pkr & 4) >> 1) | (pkr & 8);
            uint2 o2 = make_uint2(vl[d][c8 * 4 + ih * 2], vl[d][c8 * 4 + ih * 2 + 1]);
            *(uint2*)(vdst + dp) = o2;
        }
    }
}

// ---------------- MFMA flash attention, split-K, fixed-m softmax -------------
// grid (B*H, 65); block 256 = 4 waves sharing one 32-query tile, each wave
// every-4th key tile. P = exp2(st) directly (scores tiny -> no max needed);
// merge = plain sums. P-fragment from st registers, no shuffles (k-permuted Vt).
__global__ __launch_bounds__(256) void attn_mfma4(const ub16* __restrict__ qkv,
                                                  const ub16* __restrict__ Kc,
                                                  const ub16* __restrict__ Vt,
                                                  const int* __restrict__ cnt,
                                                  ub16* __restrict__ attno) {
    __shared__ float Olds[4][32][33];
    __shared__ float Oll[4][32];
    int bh = blockIdx.x, b = bh >> 3, h = bh & 7;
    int tid = threadIdx.x;
    int w = tid >> 6, lane = tid & 63, hi = lane >> 5, q = lane & 31;
    int qt = blockIdx.y;
    int t = qt * 32 + q;
    int nvalid = cnt[b] + 1;
    int nkt = (nvalid + 31) >> 5;
    int nfull = (nvalid & 31) ? nkt - 1 : nkt;

    int tc = min(t, TT - 1);
    const ub16* qp = qkv + ((size_t)(b * TT + tc)) * 768 + h * 32 + 8 * hi;
    bf16x8 bq0 = *(const bf16x8*)qp;        // Q pre-scaled by QSC in gemm epilogue
    bf16x8 bq1 = *(const bf16x8*)(qp + 16);

    float l = 0.0f;
    f32x16 ot = {};

    const ub16* kp = Kc + ((size_t)bh * NT + w) * 1024 + q * 32 + 8 * hi;
    const ub16* vp = Vt + ((size_t)bh * NT + w) * 1024 + q * 32 + 8 * hi;
    bf16x8 ka0 = *(const bf16x8*)kp;
    bf16x8 ka1 = *(const bf16x8*)(kp + 16);
    bf16x8 va0 = *(const bf16x8*)vp;
    bf16x8 va1 = *(const bf16x8*)(vp + 16);

    for (int kt = w; kt < nkt; kt += 4) {
        bf16x8 nk0 = ka0, nk1 = ka1, nv0 = va0, nv1 = va1;
        if (kt + 4 < nkt) {
            kp += 4096; vp += 4096;
            nk0 = *(const bf16x8*)kp;
            nk1 = *(const bf16x8*)(kp + 16);
            nv0 = *(const bf16x8*)vp;
            nv1 = *(const bf16x8*)(vp + 16);
        }
        f32x16 zz = {};
        f32x16 st = __builtin_amdgcn_mfma_f32_32x32x16_bf16(ka0, bq0, zz, 0, 0, 0);
        st = __builtin_amdgcn_mfma_f32_32x32x16_bf16(ka1, bq1, st, 0, 0, 0);

        if (kt >= nfull) {
            int k0 = kt << 5;
            #pragma unroll
            for (int r = 0; r < 16; ++r) {
                int key = k0 + (r & 3) + 8 * (r >> 2) + 4 * hi;
                if (key >= nvalid) st[r] = -1e30f;
            }
        }
        float tsum = 0.0f;
        #pragma unroll
        for (int r = 0; r < 16; ++r) {
            float p = exp2f(st[r]);
            st[r] = p;
            tsum += p;
        }
        tsum += __shfl_xor(tsum, 32);
        l += tsum;

        // P -> B-fragments directly from registers (k-order matches permuted Vt)
        U4B p0, p1;
        #pragma unroll
        for (int jj = 0; jj < 4; ++jj) {
            p0.u[jj] = pk2(st[2 * jj], st[2 * jj + 1]);
            p1.u[jj] = pk2(st[8 + 2 * jj], st[9 + 2 * jj]);
        }
        ot = __builtin_amdgcn_mfma_f32_32x32x16_bf16(va0, p0.v, ot, 0, 0, 0);
        ot = __builtin_amdgcn_mfma_f32_32x32x16_bf16(va1, p1.v, ot, 0, 0, 0);

        ka0 = nk0; ka1 = nk1; va0 = nv0; va1 = nv1;
    }

    // deposit per-wave partials (unnormalized)
    #pragma unroll
    for (int r = 0; r < 16; ++r) {
        int d = (r & 3) + 8 * (r >> 2) + 4 * hi;
        Olds[w][q][d] = ot[r];
    }
    if (hi == 0) Oll[w][q] = l;
    __syncthreads();

    // merge: thread -> (q row, 4-wide d group); plain sums (shared fixed m)
    int qq = tid >> 3, dg = tid & 7;
    int trow = qt * 32 + qq;
    if (trow < TT) {
        float L = Oll[0][qq] + Oll[1][qq] + Oll[2][qq] + Oll[3][qq];
        float rL = 1.0f / L;
        float o[4];
        #pragma unroll
        for (int j = 0; j < 4; ++j) {
            int d = dg * 4 + j;
            o[j] = (Olds[0][qq][d] + Olds[1][qq][d] +
                    Olds[2][qq][d] + Olds[3][qq][d]) * rL;
        }
        uint2 o2 = make_uint2(pk2(o[0], o[1]), pk2(o[2], o[3]));
        *(uint2*)(attno + ((size_t)(b * TT + trow)) * 256 + h * 32 + dg * 4) = o2;
    }
}

// ---------------- head ----------------
__global__ __launch_bounds__(512) void head_kernel(const float* __restrict__ Y,
                                                   const float* __restrict__ w1,
                                                   const float* __restrict__ b1,
                                                   const float* __restrict__ w2,
                                                   const float* __restrict__ b2,
                                                   float* __restrict__ out) {
    __shared__ float clsr[256];
    __shared__ float t1[512];
    int b = blockIdx.x, tid = threadIdx.x;
    if (tid < 256) clsr[tid] = Y[((size_t)b * TT) * DD + tid];
    __syncthreads();
    float acc = b1[tid];
    const float* w = w1 + (size_t)tid * 256;
    for (int k = 0; k < 256; ++k) acc += clsr[k] * w[k];
    t1[tid] = gelu_f(acc);
    __syncthreads();
    float acc2 = b2[tid];
    const float* wr = w2 + (size_t)tid * 512;
    for (int k = 0; k < 512; ++k) acc2 += t1[k] * wr[k];
    out[(size_t)b * 512 + tid] = acc2;
}

// ---------------- launch ----------------
extern "C" void kernel_launch(void* const* d_in, const int* in_sizes, int n_in,
                              void* d_out, int out_size, void* d_ws, size_t ws_size,
                              hipStream_t stream) {
    (void)in_sizes; (void)n_in; (void)out_size; (void)ws_size;
    const float* expr     = (const float*)d_in[0];
    const float* gene_emb = (const float*)d_in[1];
    const float* ep_w1    = (const float*)d_in[2];
    const float* ep_b1    = (const float*)d_in[3];
    const float* ep_w2    = (const float*)d_in[4];
    const float* ep_b2    = (const float*)d_in[5];
    const float* clsv     = (const float*)d_in[6];
    const float* ln1_s    = (const float*)d_in[7];
    const float* ln1_b    = (const float*)d_in[8];
    const float* qkv_w    = (const float*)d_in[9];
    const float* qkv_b    = (const float*)d_in[10];
    const float* out_w    = (const float*)d_in[11];
    const float* out_b    = (const float*)d_in[12];
    const float* ln2_s    = (const float*)d_in[13];
    const float* ln2_b    = (const float*)d_in[14];
    const float* ff_w1    = (const float*)d_in[15];
    const float* ff_b1    = (const float*)d_in[16];
    const float* ff_w2    = (const float*)d_in[17];
    const float* ff_b2    = (const float*)d_in[18];
    const float* fn_s     = (const float*)d_in[19];
    const float* fn_b     = (const float*)d_in[20];
    const float* pr_w1    = (const float*)d_in[21];
    const float* pr_b1    = (const float*)d_in[22];
    const float* pr_w2    = (const float*)d_in[23];
    const float* pr_b2    = (const float*)d_in[24];
    float* outp = (float*)d_out;

    const size_t KVSZ = (size_t)32 * NT * 1024;

    // workspace layout
    float* x   = (float*)d_ws;                       // BT*256 f32
    float* VAL = x + (size_t)BT * 256;               // 8192*256 f32; reused as Vt + final-LN out
    ub16* y16   = (ub16*)(VAL + (size_t)8192 * 256);
    ub16* qkv16 = y16 + (size_t)BT * 256;
    ub16* att16 = qkv16 + (size_t)BT * 768;
    ub16* ff116 = att16 + (size_t)BT * 256;
    ub16* kc_h  = ff116 + (size_t)BT * 1024;
    ub16* wqkv  = kc_h + KVSZ;
    ub16* wout  = wqkv + (size_t)LL * 768 * 256;
    ub16* wff1  = wout + (size_t)LL * 256 * 256;
    ub16* wff2  = wff1 + (size_t)LL * 1024 * 256;
    ub16* wep2  = wff2 + (size_t)LL * 256 * 1024;
    int*  idxb  = (int*)(wep2 + (size_t)256 * 256);
    int*  cntb  = idxb + BB * KK;
    ub16* H16 = kc_h;
    ub16* Kc  = kc_h;
    ub16* Vt  = (ub16*)VAL;

    // 1) top-K
    topk_kernel<<<BB, 1024, 0, stream>>>(expr, idxb, cntb);

    // 2) weights -> bf16
    cvt_bf16_kernel<<<(LL*768*256 + 255)/256, 256, 0, stream>>>(qkv_w, wqkv, LL*768*256);
    cvt_bf16_kernel<<<(LL*256*256 + 255)/256, 256, 0, stream>>>(out_w, wout, LL*256*256);
    cvt_bf16_kernel<<<(LL*1024*256 + 255)/256, 256, 0, stream>>>(ff_w1, wff1, LL*1024*256);
    cvt_bf16_kernel<<<(LL*256*1024 + 255)/256, 256, 0, stream>>>(ff_w2, wff2, LL*256*1024);
    cvt_bf16_kernel<<<(256*256 + 255)/256, 256, 0, stream>>>(ep_w2, wep2, 256*256);

    // 3) token embeddings
    build_h_kernel<<<(BB * KK * DD) / 256, 256, 0, stream>>>(expr, idxb, cntb, ep_w1, ep_b1, H16);
    gemm_bt16<<<dim3(4, 128), 256, 0, stream>>>(H16, wep2, ep_b2, nullptr, VAL, nullptr,
                                                8192, 256, 256, 0, 0);
    assemble_kernel<<<BT, 256, 0, stream>>>(VAL, gene_emb, clsv, idxb, cntb, x);

    // 4) transformer layers
    for (int i = 0; i < LL; ++i) {
        ln_kernel<<<BT / 4, 256, 0, stream>>>(x, ln1_s + i * DD, ln1_b + i * DD, y16, nullptr);
        gemm_bt16<<<dim3(12, 129), 256, 0, stream>>>(y16, wqkv + (size_t)i * 768 * 256,
                                                     qkv_b + i * 768, nullptr, nullptr, qkv16,
                                                     BT, 768, 256, 0, 256);
        kvprep<<<dim3(BB * HH, 33), 256, 0, stream>>>(qkv16, Kc, Vt);
        attn_mfma4<<<dim3(BB * HH, NT), 256, 0, stream>>>(qkv16, Kc, Vt, cntb, att16);
        gemm_bt16<<<dim3(4, 129), 256, 0, stream>>>(att16, wout + (size_t)i * 256 * 256,
                                                    out_b + i * 256, x, x, nullptr,
                                                    BT, 256, 256, 0, 0);
        ln_kernel<<<BT / 4, 256, 0, stream>>>(x, ln2_s + i * DD, ln2_b + i * DD, y16, nullptr);
        gemm_bt16<<<dim3(16, 129), 256, 0, stream>>>(y16, wff1 + (size_t)i * 1024 * 256,
                                                     ff_b1 + i * 1024, nullptr, nullptr, ff116,
                                                     BT, 1024, 256, 1, 0);
        gemm_bt16<<<dim3(4, 129), 256, 0, stream>>>(ff116, wff2 + (size_t)i * 256 * 1024,
                                                    ff_b2 + i * 256, x, x, nullptr,
                                                    BT, 256, 1024, 0, 0);
    }

    // 5) final LN + head
    ln_kernel<<<BT / 4, 256, 0, stream>>>(x, fn_s, fn_b, nullptr, VAL);
    head_kernel<<<BB, 512, 0, stream>>>(VAL, pr_w1, pr_b1, pr_w2, pr_b2, outp);
}